// Round 15
// baseline (442.343 us; speedup 1.0000x reference)
//
#include <hip/hip_runtime.h>

#define NN 50000
#define NE 800000
#define TOTN (2 * NN)
#define NG 64
#define DD 128
#define NL 3
#define ZW (2 * DD * NL)  // 768
#define NB2 128           // sub-buckets per channel (CSR build)
#define NPB 391           // nodes per bucket
#define CAP2 8192         // pair capacity per bucket
#define CHUNK 4096        // edges per pass-1 block
#define P1B 196           // pass-1 blocks per channel
#define GEMB 3136         // gemm blocks per channel (one 16-row tile each)
#define TILES 3125        // 16-row tiles per channel
#define AGGB 6256         // agg blocks: 782*8, XCD-affine (4 XCDs per channel)
#define CVTX (TOTN * DD / 8 / 256)  // 6250 cvt_x blocks

typedef __attribute__((ext_vector_type(8))) short short8;
typedef __attribute__((ext_vector_type(4))) float f32x4;
typedef __attribute__((ext_vector_type(4))) unsigned int uint4v;

__device__ inline unsigned short f2bf(float f) {
  unsigned int u = __float_as_uint(f);
  unsigned int r = (u + 0x7fffu + ((u >> 16) & 1u)) >> 16;
  return (unsigned short)r;
}
__device__ inline float bflo(unsigned int u) { return __uint_as_float(u << 16); }
__device__ inline float bfhi(unsigned int u) { return __uint_as_float(u & 0xffff0000u); }

// ---------------- prep: cvt_x || cvt_wt || bucket (role-split) ----------------
__global__ __launch_bounds__(256) void prep_kernel(
    const float* __restrict__ x1, const float* __restrict__ x2,
    unsigned short* __restrict__ X,
    const float* __restrict__ p0, const float* __restrict__ p1,
    const float* __restrict__ p2, const float* __restrict__ p3,
    unsigned short* __restrict__ WT,
    const int* __restrict__ e1, const int* __restrict__ e2,
    int* __restrict__ bcur, uint2* __restrict__ pairs) {
  int bid = blockIdx.x;
  if (bid < CVTX) {
    // ---- cvt_x: fp32 x1/x2 -> bf16 node-major, 8 elems/thread ----
    int i = bid * 256 + threadIdx.x;
    const int per = NN * DD / 8;
    int ch = i >= per;
    const float* x = ch ? x2 : x1;
    int il = i - ch * per;
    const float4* in4 = reinterpret_cast<const float4*>(x);
    float4 a = in4[2 * il], b = in4[2 * il + 1];
    uint4 o;
    o.x = (unsigned int)f2bf(a.x) | ((unsigned int)f2bf(a.y) << 16);
    o.y = (unsigned int)f2bf(a.z) | ((unsigned int)f2bf(a.w) << 16);
    o.z = (unsigned int)f2bf(b.x) | ((unsigned int)f2bf(b.y) << 16);
    o.w = (unsigned int)f2bf(b.z) | ((unsigned int)f2bf(b.w) << 16);
    reinterpret_cast<uint4*>(X)[i] = o;
    return;
  }
  if (bid < CVTX + 192) {
    // ---- cvt_wt: 12 mats fp32 [k][c] -> bf16 [c][k] ----
    __shared__ float tile[32][33];
    int idx = bid - CVTX;
    int k0 = (idx & 3) * 32, c0 = ((idx >> 2) & 3) * 32, slot = idx >> 4;
    int grp = slot / 3, mat = slot % 3;
    const float* ip = (grp == 0 ? p0 : grp == 1 ? p1 : grp == 2 ? p2 : p3) + mat * 16384;
    unsigned short* op = WT + slot * 16384;
    int tx = threadIdx.x & 31, ty = threadIdx.x >> 5;
#pragma unroll
    for (int rr = 0; rr < 32; rr += 8)
      tile[ty + rr][tx] = ip[(k0 + ty + rr) * 128 + (c0 + tx)];
    __syncthreads();
#pragma unroll
    for (int rr = 0; rr < 32; rr += 8)
      op[(c0 + ty + rr) * 128 + (k0 + tx)] = f2bf(tile[tx][ty + rr]);
    return;
  }
  {
    // ---- bucket: edges by dst range ----
    int blk = bid - (CVTX + 192);
    int ch = blk >= P1B;
    blk -= ch * P1B;
    const int* E = ch ? e2 : e1;
    int base = blk * CHUNK;
    __shared__ int lcnt[NB2], gbase[NB2];
    for (int i = threadIdx.x; i < NB2; i += 256) lcnt[i] = 0;
    __syncthreads();
    int srcv[16], dstv[16], lrank[16];
#pragma unroll
    for (int k = 0; k < 16; k++) {
      int e = base + k * 256 + threadIdx.x;
      if (e < NE) {
        srcv[k] = E[e];
        dstv[k] = E[NE + e];
        lrank[k] = atomicAdd(&lcnt[dstv[k] / NPB], 1);
      } else dstv[k] = -1;
    }
    __syncthreads();
    for (int i = threadIdx.x; i < NB2; i += 256)
      gbase[i] = atomicAdd(&bcur[ch * NB2 + i], lcnt[i]);
    __syncthreads();
#pragma unroll
    for (int k = 0; k < 16; k++)
      if (dstv[k] >= 0) {
        int g = dstv[k] / NPB;
        pairs[(size_t)(ch * NB2 + g) * CAP2 + gbase[g] + lrank[k]] =
            make_uint2((unsigned)srcv[k], (unsigned)dstv[k]);
      }
  }
}

// ---------------- CSR build pass 2 (inline colbase scan) + gstart block ----------------
__global__ __launch_bounds__(256) void csr_build_kernel(const uint2* __restrict__ pairs,
                                                        const int* __restrict__ bcur,
                                                        int* __restrict__ rowptr,
                                                        int* __restrict__ col,
                                                        const int* __restrict__ batch1,
                                                        const int* __restrict__ batch2,
                                                        int* __restrict__ gstart) {
  if (blockIdx.x == 256) {  // gstart role
    int t = threadIdx.x;
    if (t >= 2 * (NG + 1)) return;
    int ch = t / (NG + 1), g = t % (NG + 1);
    const int* b = ch ? batch2 : batch1;
    int lo = 0, hi = NN;
    while (lo < hi) {
      int m = (lo + hi) >> 1;
      if (b[m] < g) lo = m + 1; else hi = m;
    }
    gstart[t] = lo;
    return;
  }
  int g = blockIdx.x;
  int ch = g >> 7, b = g & 127;
  int tid = threadIdx.x;
  __shared__ int sc[128];
  if (tid < 128) sc[tid] = bcur[ch * 128 + tid];
  __syncthreads();
  for (int o = 1; o < 128; o <<= 1) {
    int t = (tid < 128 && tid >= o) ? sc[tid - o] : 0;
    __syncthreads();
    if (tid < 128) sc[tid] += t;
    __syncthreads();
  }
  int count = bcur[g];
  int base = sc[b] - count;  // exclusive prefix within channel
  int node0 = b * NPB;
  int nloc = min(NPB, NN - node0);
  const uint2* p = pairs + (size_t)g * CAP2;
  __shared__ int hist[512], pref[512], cur[512], stmp[256];
  for (int i = tid; i < 512; i += 256) hist[i] = 0;
  __syncthreads();
  for (int e = tid; e < count; e += 256)
    atomicAdd(&hist[(int)p[e].y - node0], 1);
  __syncthreads();
  int a0 = hist[2 * tid], a1 = hist[2 * tid + 1];
  int sum = a0 + a1;
  stmp[tid] = sum;
  __syncthreads();
  for (int o = 1; o < 256; o <<= 1) {
    int tv = (tid >= o) ? stmp[tid - o] : 0;
    __syncthreads();
    stmp[tid] += tv;
    __syncthreads();
  }
  int ex = stmp[tid] - sum;
  pref[2 * tid] = ex;       pref[2 * tid + 1] = ex + a0;
  cur[2 * tid] = ex;        cur[2 * tid + 1] = ex + a0;
  __syncthreads();
  for (int i = tid; i < nloc; i += 256)
    rowptr[ch * (NN + 1) + node0 + i] = base + pref[i];
  if (tid == 0 && b == NB2 - 1) rowptr[ch * (NN + 1) + NN] = base + count;
  for (int e = tid; e < count; e += 256) {
    uint2 pr = p[e];
    int pos = atomicAdd(&cur[(int)pr.y - node0], 1);
    col[ch * NE + base + pos] = (int)pr.x;
  }
}

// ---------------- agg (+ fused pool of the PREVIOUS layer's output) ----------------
__global__ __launch_bounds__(256) void agg_pool_kernel(const unsigned short* __restrict__ X,
                                                       const int* __restrict__ rowptr,
                                                       const int* __restrict__ col,
                                                       unsigned short* __restrict__ Y,
                                                       const unsigned short* __restrict__ Xprev,
                                                       const int* __restrict__ gstart,
                                                       float* __restrict__ z, int layerPrev) {
  if (blockIdx.x >= AGGB) {
    // ---- pool role ----
    int pb = blockIdx.x - AGGB;
    int ch = pb >> 6, g = pb & 63;
    int r0 = gstart[ch * (NG + 1) + g], r1 = gstart[ch * (NG + 1) + g + 1];
    int c8 = threadIdx.x & 15, part = threadIdx.x >> 4;
    const uint4* X4 = reinterpret_cast<const uint4*>(Xprev);
    size_t base = (size_t)ch * NN * 16 + c8;
    float acc[8];
#pragma unroll
    for (int q = 0; q < 8; q++) acc[q] = 0.f;
    int r = r0 + part;
    for (; r + 48 < r1; r += 64) {
      uint4 v0 = X4[base + (size_t)r * 16];
      uint4 v1 = X4[base + (size_t)(r + 16) * 16];
      uint4 v2 = X4[base + (size_t)(r + 32) * 16];
      uint4 v3 = X4[base + (size_t)(r + 48) * 16];
      unsigned int w0[4] = {v0.x, v0.y, v0.z, v0.w};
      unsigned int w1[4] = {v1.x, v1.y, v1.z, v1.w};
      unsigned int w2[4] = {v2.x, v2.y, v2.z, v2.w};
      unsigned int w3[4] = {v3.x, v3.y, v3.z, v3.w};
#pragma unroll
      for (int q = 0; q < 4; q++) {
        acc[2 * q]     += bflo(w0[q]) + bflo(w1[q]) + bflo(w2[q]) + bflo(w3[q]);
        acc[2 * q + 1] += bfhi(w0[q]) + bfhi(w1[q]) + bfhi(w2[q]) + bfhi(w3[q]);
      }
    }
    for (; r < r1; r += 16) {
      uint4 v = X4[base + (size_t)r * 16];
      unsigned int w[4] = {v.x, v.y, v.z, v.w};
#pragma unroll
      for (int q = 0; q < 4; q++) {
        acc[2 * q]     += bflo(w[q]);
        acc[2 * q + 1] += bfhi(w[q]);
      }
    }
    __shared__ float zacc[16][128];
#pragma unroll
    for (int q = 0; q < 8; q++) zacc[part][c8 * 8 + q] = acc[q];
    __syncthreads();
    for (int s = 8; s > 0; s >>= 1) {
      if (part < s) {
#pragma unroll
        for (int q = 0; q < 8; q++)
          zacc[part][c8 * 8 + q] += zacc[part + s][c8 * 8 + q];
      }
      __syncthreads();
    }
    if (part == 0) {
#pragma unroll
      for (int q = 0; q < 8; q++) {
        int colw = c8 * 8 + q;
        z[(size_t)g * ZW + ch * DD * NL + layerPrev * DD + colw] = zacc[0][colw];
      }
    }
    return;
  }
  // ---- agg role: XCD-channel-affine, 8-deep pipelined gather ----
  int ch = ((blockIdx.x & 7) >= 4);          // XCDs 0-3 -> ch0, 4-7 -> ch1
  int tile = (blockIdx.x >> 3) * 4 + (blockIdx.x & 3);
  if (tile >= TILES) return;                 // 3 spare blocks per channel
  int nl = tile * 16 + (threadIdx.x >> 4);   // node within channel
  int node = ch * NN + nl;
  int lane = threadIdx.x & 15;
  const int* rp = rowptr + ch * (NN + 1);
  const int* cl = col + ch * NE;
  const uint4* X4 = reinterpret_cast<const uint4*>(X);
  size_t chbase = (size_t)ch * NN * 16;
  float acc[8];
  {
    uint4 sv = X4[(size_t)node * 16 + lane];
    unsigned int w[4] = {sv.x, sv.y, sv.z, sv.w};
#pragma unroll
    for (int q = 0; q < 4; q++) {
      acc[2 * q]     = bflo(w[q]);
      acc[2 * q + 1] = bfhi(w[q]);
    }
  }
  int s = rp[nl], e = rp[nl + 1];
  int j = s;
  for (; j + 8 <= e; j += 8) {
    uint4 v[8];
#pragma unroll
    for (int q = 0; q < 8; q++)
      v[q] = X4[chbase + (size_t)cl[j + q] * 16 + lane];
#pragma unroll
    for (int q = 0; q < 8; q++) {
      unsigned int w[4] = {v[q].x, v[q].y, v[q].z, v[q].w};
#pragma unroll
      for (int u = 0; u < 4; u++) {
        acc[2 * u]     += bflo(w[u]);
        acc[2 * u + 1] += bfhi(w[u]);
      }
    }
  }
  for (; j < e; ++j) {
    uint4 v = X4[chbase + (size_t)cl[j] * 16 + lane];
    unsigned int w[4] = {v.x, v.y, v.z, v.w};
#pragma unroll
    for (int u = 0; u < 4; u++) {
      acc[2 * u]     += bflo(w[u]);
      acc[2 * u + 1] += bfhi(w[u]);
    }
  }
  uint4v o;
  o.x = (unsigned int)f2bf(acc[0]) | ((unsigned int)f2bf(acc[1]) << 16);
  o.y = (unsigned int)f2bf(acc[2]) | ((unsigned int)f2bf(acc[3]) << 16);
  o.z = (unsigned int)f2bf(acc[4]) | ((unsigned int)f2bf(acc[5]) << 16);
  o.w = (unsigned int)f2bf(acc[6]) | ((unsigned int)f2bf(acc[7]) << 16);
  __builtin_nontemporal_store(o, reinterpret_cast<uint4v*>(Y) + (size_t)node * 16 + lane);
}

// ---------------- fused MLP: one 16-row tile per block, single barrier ----------------
__global__ __launch_bounds__(256) void gemm_fused_kernel(
    const unsigned short* __restrict__ Y, unsigned short* __restrict__ X,
    const unsigned short* __restrict__ WT,
    const float* __restrict__ b1c1, const float* __restrict__ b1c2,
    const float* __restrict__ b2c1, const float* __restrict__ b2c2,
    const float* __restrict__ bng, const float* __restrict__ bnb,
    const float* __restrict__ bnm, const float* __restrict__ bnv, int layer) {
  __shared__ unsigned short hlds[16][136];
  int ch = blockIdx.x >= GEMB;
  int t = blockIdx.x - ch * GEMB;
  if (t >= TILES) return;
  int lane = threadIdx.x & 63, wv = threadIdx.x >> 6;
  int l15 = lane & 15, lk = lane >> 4;
  int c0 = wv * 32;
  size_t r0g = (size_t)ch * NN + t * 16;
  // A loads first (Y-read latency overlaps the W fetch below)
  const unsigned short* yp = Y + (r0g + l15) * 128 + lk * 8;
  short8 a0 = *reinterpret_cast<const short8*>(yp);
  short8 a1 = *reinterpret_cast<const short8*>(yp + 32);
  short8 a2 = *reinterpret_cast<const short8*>(yp + 64);
  short8 a3 = *reinterpret_cast<const short8*>(yp + 96);
  const unsigned short* W1 = WT + (size_t)(ch * 6 + layer) * 16384;
  const unsigned short* W2 = WT + (size_t)(ch * 6 + 3 + layer) * 16384;
  short8 w1f[2][4], w2f[2][4];
#pragma unroll
  for (int ct = 0; ct < 2; ct++)
#pragma unroll
    for (int kk = 0; kk < 4; kk++) {
      size_t boff = (size_t)(c0 + ct * 16 + l15) * 128 + kk * 32 + lk * 8;
      w1f[ct][kk] = *reinterpret_cast<const short8*>(W1 + boff);
      w2f[ct][kk] = *reinterpret_cast<const short8*>(W2 + boff);
    }
  const float* b1 = (ch ? b1c2 : b1c1) + layer * DD;
  const float* b2 = (ch ? b2c2 : b2c1) + layer * DD;
  float sc1[2], sh1[2], sh2[2];
#pragma unroll
  for (int ct = 0; ct < 2; ct++) {
    int colg = c0 + ct * 16 + l15;
    if (!ch) {
      float s = bng[layer * DD + colg] * rsqrtf(bnv[layer * DD + colg] + 1e-5f);
      sc1[ct] = s;
      sh1[ct] = (b1[colg] - bnm[layer * DD + colg]) * s + bnb[layer * DD + colg];
    } else {
      sc1[ct] = 1.f;
      sh1[ct] = b1[colg];
    }
    sh2[ct] = b2[colg];
  }
#pragma unroll
  for (int ct = 0; ct < 2; ct++) {
    f32x4 acc = {0.f, 0.f, 0.f, 0.f};
    acc = __builtin_amdgcn_mfma_f32_16x16x32_bf16(a0, w1f[ct][0], acc, 0, 0, 0);
    acc = __builtin_amdgcn_mfma_f32_16x16x32_bf16(a1, w1f[ct][1], acc, 0, 0, 0);
    acc = __builtin_amdgcn_mfma_f32_16x16x32_bf16(a2, w1f[ct][2], acc, 0, 0, 0);
    acc = __builtin_amdgcn_mfma_f32_16x16x32_bf16(a3, w1f[ct][3], acc, 0, 0, 0);
    int colg = c0 + ct * 16 + l15;
#pragma unroll
    for (int r = 0; r < 4; r++) {
      float tv = fmaxf(acc[r] * sc1[ct] + sh1[ct], 0.f);
      hlds[lk * 4 + r][colg] = f2bf(tv);
    }
  }
  __syncthreads();
  short8 h0 = *reinterpret_cast<const short8*>(&hlds[l15][lk * 8]);
  short8 h1 = *reinterpret_cast<const short8*>(&hlds[l15][32 + lk * 8]);
  short8 h2 = *reinterpret_cast<const short8*>(&hlds[l15][64 + lk * 8]);
  short8 h3 = *reinterpret_cast<const short8*>(&hlds[l15][96 + lk * 8]);
#pragma unroll
  for (int ct = 0; ct < 2; ct++) {
    f32x4 acc = {0.f, 0.f, 0.f, 0.f};
    acc = __builtin_amdgcn_mfma_f32_16x16x32_bf16(h0, w2f[ct][0], acc, 0, 0, 0);
    acc = __builtin_amdgcn_mfma_f32_16x16x32_bf16(h1, w2f[ct][1], acc, 0, 0, 0);
    acc = __builtin_amdgcn_mfma_f32_16x16x32_bf16(h2, w2f[ct][2], acc, 0, 0, 0);
    acc = __builtin_amdgcn_mfma_f32_16x16x32_bf16(h3, w2f[ct][3], acc, 0, 0, 0);
    int colg = c0 + ct * 16 + l15;
#pragma unroll
    for (int r = 0; r < 4; r++) {
      float tv = acc[r] + sh2[ct];
      if (!ch) tv = fmaxf(tv, 0.f);
      else     tv = tv > 0.f ? tv : 0.01f * tv;
      X[(r0g + lk * 4 + r) * 128 + colg] = f2bf(tv);
    }
  }
}

// ---------------- standalone pool (last layer) ----------------
__global__ __launch_bounds__(256) void pool_kernel(const unsigned short* __restrict__ X,
                                                   const int* __restrict__ gstart,
                                                   float* __restrict__ z, int layer) {
  int ch = blockIdx.x >> 6, g = blockIdx.x & 63;
  int r0 = gstart[ch * (NG + 1) + g], r1 = gstart[ch * (NG + 1) + g + 1];
  int c8 = threadIdx.x & 15, part = threadIdx.x >> 4;
  const uint4* X4 = reinterpret_cast<const uint4*>(X);
  size_t base = (size_t)ch * NN * 16 + c8;
  float acc[8];
#pragma unroll
  for (int q = 0; q < 8; q++) acc[q] = 0.f;
  int r = r0 + part;
  for (; r + 48 < r1; r += 64) {
    uint4 v0 = X4[base + (size_t)r * 16];
    uint4 v1 = X4[base + (size_t)(r + 16) * 16];
    uint4 v2 = X4[base + (size_t)(r + 32) * 16];
    uint4 v3 = X4[base + (size_t)(r + 48) * 16];
    unsigned int w0[4] = {v0.x, v0.y, v0.z, v0.w};
    unsigned int w1[4] = {v1.x, v1.y, v1.z, v1.w};
    unsigned int w2[4] = {v2.x, v2.y, v2.z, v2.w};
    unsigned int w3[4] = {v3.x, v3.y, v3.z, v3.w};
#pragma unroll
    for (int q = 0; q < 4; q++) {
      acc[2 * q]     += bflo(w0[q]) + bflo(w1[q]) + bflo(w2[q]) + bflo(w3[q]);
      acc[2 * q + 1] += bfhi(w0[q]) + bfhi(w1[q]) + bfhi(w2[q]) + bfhi(w3[q]);
    }
  }
  for (; r < r1; r += 16) {
    uint4 v = X4[base + (size_t)r * 16];
    unsigned int w[4] = {v.x, v.y, v.z, v.w};
#pragma unroll
    for (int q = 0; q < 4; q++) {
      acc[2 * q]     += bflo(w[q]);
      acc[2 * q + 1] += bfhi(w[q]);
    }
  }
  __shared__ float zacc[16][128];
#pragma unroll
  for (int q = 0; q < 8; q++) zacc[part][c8 * 8 + q] = acc[q];
  __syncthreads();
  for (int s = 8; s > 0; s >>= 1) {
    if (part < s) {
#pragma unroll
      for (int q = 0; q < 8; q++)
        zacc[part][c8 * 8 + q] += zacc[part + s][c8 * 8 + q];
    }
    __syncthreads();
  }
  if (part == 0) {
#pragma unroll
    for (int q = 0; q < 8; q++) {
      int colw = c8 * 8 + q;
      z[(size_t)g * ZW + ch * DD * NL + layer * DD + colw] = zacc[0][colw];
    }
  }
}

// ---------------- head ----------------
__global__ __launch_bounds__(128) void head_kernel(const float* __restrict__ z,
                                                   const float* __restrict__ Wf1,
                                                   const float* __restrict__ bf1,
                                                   const float* __restrict__ Wf2,
                                                   const float* __restrict__ bf2,
                                                   float* __restrict__ out) {
  int g = blockIdx.x, t = threadIdx.x;
  const float* zr = z + (size_t)g * ZW;
  float acc = bf1[t];
  for (int j = 0; j < ZW; ++j) acc += zr[j] * Wf1[(size_t)j * DD + t];
  float h = fmaxf(acc, 0.f);
  __shared__ float red[128];
  red[t] = h * Wf2[t];
  __syncthreads();
  for (int s = 64; s > 0; s >>= 1) {
    if (t < s) red[t] += red[t + s];
    __syncthreads();
  }
  if (t == 0) out[g] = red[0] + bf2[0];
}

extern "C" void kernel_launch(void* const* d_in, const int* in_sizes, int n_in,
                              void* d_out, int out_size, void* d_ws, size_t ws_size,
                              hipStream_t stream) {
  const float* x1   = (const float*)d_in[0];
  const float* x2   = (const float*)d_in[1];
  const float* W1c1 = (const float*)d_in[2];
  const float* b1c1 = (const float*)d_in[3];
  const float* bng  = (const float*)d_in[4];
  const float* bnb  = (const float*)d_in[5];
  const float* bnm  = (const float*)d_in[6];
  const float* bnv  = (const float*)d_in[7];
  const float* W2c1 = (const float*)d_in[8];
  const float* b2c1 = (const float*)d_in[9];
  const float* W1c2 = (const float*)d_in[10];
  const float* b1c2 = (const float*)d_in[11];
  const float* W2c2 = (const float*)d_in[12];
  const float* b2c2 = (const float*)d_in[13];
  const float* Wf1  = (const float*)d_in[14];
  const float* bf1  = (const float*)d_in[15];
  const float* Wf2  = (const float*)d_in[16];
  const float* bf2  = (const float*)d_in[17];
  const int* edge1  = (const int*)d_in[18];
  const int* edge2  = (const int*)d_in[19];
  const int* batch1 = (const int*)d_in[20];
  const int* batch2 = (const int*)d_in[21];
  (void)ws_size; (void)n_in; (void)in_sizes; (void)out_size;

  char* ws = (char*)d_ws;
  const size_t NB16 = (size_t)TOTN * DD * 2;  // 25.6 MB node buffer
  unsigned short* bufA = (unsigned short*)(ws);
  unsigned short* bufB = (unsigned short*)(ws + NB16);
  unsigned short* bufY = (unsigned short*)(ws + 2 * NB16);
  size_t off = 3 * NB16;
  unsigned short* WT = (unsigned short*)(ws + off); off += (size_t)12 * 16384 * 2;
  uint2* pairs = (uint2*)(ws + off); off += (size_t)2 * NB2 * CAP2 * 8;
  int* col     = (int*)(ws + off); off += (size_t)2 * NE * 4;
  int* rowptr  = (int*)(ws + off); off += (((size_t)2 * (NN + 1) * 4) + 255) & ~(size_t)255;
  int* bcur    = (int*)(ws + off); off += 256 * 4;
  int* gstart  = (int*)(ws + off); off += 256 * 4;
  float* z     = (float*)(ws + off); off += (size_t)NG * ZW * 4;

  (void)hipMemsetAsync(bcur, 0, 256 * 4, stream);
  prep_kernel<<<CVTX + 192 + 2 * P1B, 256, 0, stream>>>(
      x1, x2, bufA, W1c1, W2c1, W1c2, W2c2, WT, edge1, edge2, bcur, pairs);
  csr_build_kernel<<<257, 256, 0, stream>>>(pairs, bcur, rowptr, col, batch1, batch2, gstart);

  unsigned short* cin = bufA;
  unsigned short* cout = bufB;
  for (int i = 0; i < NL; ++i) {
    int grid = (i == 0) ? AGGB : AGGB + 2 * NG;  // layers 1,2 carry prev layer's pool
    agg_pool_kernel<<<grid, 256, 0, stream>>>(cin, rowptr, col, bufY,
                                              cin, gstart, z, i - 1);
    gemm_fused_kernel<<<2 * GEMB, 256, 0, stream>>>(bufY, cout, WT,
                                                    b1c1, b1c2, b2c1, b2c2,
                                                    bng, bnb, bnm, bnv, i);
    unsigned short* tmp = cin; cin = cout; cout = tmp;
  }
  pool_kernel<<<2 * NG, 256, 0, stream>>>(cin, gstart, z, NL - 1);
  head_kernel<<<NG, 128, 0, stream>>>(z, Wf1, bf1, Wf2, bf2, (float*)d_out);
}

// Round 16
// 372.051 us; speedup vs baseline: 1.1889x; 1.1889x over previous
//
#include <hip/hip_runtime.h>

#define NN 50000
#define NE 800000
#define TOTN (2 * NN)
#define NG 64
#define DD 128
#define NL 3
#define ZW (2 * DD * NL)  // 768
#define NB2 128           // sub-buckets per channel (CSR build)
#define NPB 391           // nodes per bucket
#define CAP2 8192         // pair capacity per bucket
#define CHUNK 4096        // edges per pass-1 block
#define P1B 196           // pass-1 blocks per channel
#define GB2 1024          // gemm blocks per channel (grid-stride, ~3 tiles each)
#define TILES 3125        // 16-row tiles per channel
#define AGGB 6256         // agg blocks: 782*8, XCD-affine (4 XCDs per channel)
#define CVTX (TOTN * DD / 8 / 256)  // 6250 cvt_x blocks

typedef __attribute__((ext_vector_type(8))) short short8;
typedef __attribute__((ext_vector_type(4))) float f32x4;
typedef __attribute__((ext_vector_type(4))) unsigned int uint4v;

__device__ inline unsigned short f2bf(float f) {
  unsigned int u = __float_as_uint(f);
  unsigned int r = (u + 0x7fffu + ((u >> 16) & 1u)) >> 16;
  return (unsigned short)r;
}
__device__ inline float bflo(unsigned int u) { return __uint_as_float(u << 16); }
__device__ inline float bfhi(unsigned int u) { return __uint_as_float(u & 0xffff0000u); }

// ---------------- prep: cvt_x || cvt_wt || bucket (role-split) ----------------
__global__ __launch_bounds__(256) void prep_kernel(
    const float* __restrict__ x1, const float* __restrict__ x2,
    unsigned short* __restrict__ X,
    const float* __restrict__ p0, const float* __restrict__ p1,
    const float* __restrict__ p2, const float* __restrict__ p3,
    unsigned short* __restrict__ WT,
    const int* __restrict__ e1, const int* __restrict__ e2,
    int* __restrict__ bcur, uint2* __restrict__ pairs) {
  int bid = blockIdx.x;
  if (bid < CVTX) {
    // ---- cvt_x: fp32 x1/x2 -> bf16 node-major, 8 elems/thread ----
    int i = bid * 256 + threadIdx.x;
    const int per = NN * DD / 8;
    int ch = i >= per;
    const float* x = ch ? x2 : x1;
    int il = i - ch * per;
    const float4* in4 = reinterpret_cast<const float4*>(x);
    float4 a = in4[2 * il], b = in4[2 * il + 1];
    uint4 o;
    o.x = (unsigned int)f2bf(a.x) | ((unsigned int)f2bf(a.y) << 16);
    o.y = (unsigned int)f2bf(a.z) | ((unsigned int)f2bf(a.w) << 16);
    o.z = (unsigned int)f2bf(b.x) | ((unsigned int)f2bf(b.y) << 16);
    o.w = (unsigned int)f2bf(b.z) | ((unsigned int)f2bf(b.w) << 16);
    reinterpret_cast<uint4*>(X)[i] = o;
    return;
  }
  if (bid < CVTX + 192) {
    // ---- cvt_wt: 12 mats fp32 [k][c] -> bf16 [c][k] ----
    __shared__ float tile[32][33];
    int idx = bid - CVTX;
    int k0 = (idx & 3) * 32, c0 = ((idx >> 2) & 3) * 32, slot = idx >> 4;
    int grp = slot / 3, mat = slot % 3;
    const float* ip = (grp == 0 ? p0 : grp == 1 ? p1 : grp == 2 ? p2 : p3) + mat * 16384;
    unsigned short* op = WT + slot * 16384;
    int tx = threadIdx.x & 31, ty = threadIdx.x >> 5;
#pragma unroll
    for (int rr = 0; rr < 32; rr += 8)
      tile[ty + rr][tx] = ip[(k0 + ty + rr) * 128 + (c0 + tx)];
    __syncthreads();
#pragma unroll
    for (int rr = 0; rr < 32; rr += 8)
      op[(c0 + ty + rr) * 128 + (k0 + tx)] = f2bf(tile[tx][ty + rr]);
    return;
  }
  {
    // ---- bucket: edges by dst range ----
    int blk = bid - (CVTX + 192);
    int ch = blk >= P1B;
    blk -= ch * P1B;
    const int* E = ch ? e2 : e1;
    int base = blk * CHUNK;
    __shared__ int lcnt[NB2], gbase[NB2];
    for (int i = threadIdx.x; i < NB2; i += 256) lcnt[i] = 0;
    __syncthreads();
    int srcv[16], dstv[16], lrank[16];
#pragma unroll
    for (int k = 0; k < 16; k++) {
      int e = base + k * 256 + threadIdx.x;
      if (e < NE) {
        srcv[k] = E[e];
        dstv[k] = E[NE + e];
        lrank[k] = atomicAdd(&lcnt[dstv[k] / NPB], 1);
      } else dstv[k] = -1;
    }
    __syncthreads();
    for (int i = threadIdx.x; i < NB2; i += 256)
      gbase[i] = atomicAdd(&bcur[ch * NB2 + i], lcnt[i]);
    __syncthreads();
#pragma unroll
    for (int k = 0; k < 16; k++)
      if (dstv[k] >= 0) {
        int g = dstv[k] / NPB;
        pairs[(size_t)(ch * NB2 + g) * CAP2 + gbase[g] + lrank[k]] =
            make_uint2((unsigned)srcv[k], (unsigned)dstv[k]);
      }
  }
}

// ---------------- CSR build pass 2 (inline colbase scan) + gstart block ----------------
__global__ __launch_bounds__(256) void csr_build_kernel(const uint2* __restrict__ pairs,
                                                        const int* __restrict__ bcur,
                                                        int* __restrict__ rowptr,
                                                        int* __restrict__ col,
                                                        const int* __restrict__ batch1,
                                                        const int* __restrict__ batch2,
                                                        int* __restrict__ gstart) {
  if (blockIdx.x == 256) {  // gstart role
    int t = threadIdx.x;
    if (t >= 2 * (NG + 1)) return;
    int ch = t / (NG + 1), g = t % (NG + 1);
    const int* b = ch ? batch2 : batch1;
    int lo = 0, hi = NN;
    while (lo < hi) {
      int m = (lo + hi) >> 1;
      if (b[m] < g) lo = m + 1; else hi = m;
    }
    gstart[t] = lo;
    return;
  }
  int g = blockIdx.x;
  int ch = g >> 7, b = g & 127;
  int tid = threadIdx.x;
  __shared__ int sc[128];
  if (tid < 128) sc[tid] = bcur[ch * 128 + tid];
  __syncthreads();
  for (int o = 1; o < 128; o <<= 1) {
    int t = (tid < 128 && tid >= o) ? sc[tid - o] : 0;
    __syncthreads();
    if (tid < 128) sc[tid] += t;
    __syncthreads();
  }
  int count = bcur[g];
  int base = sc[b] - count;  // exclusive prefix within channel
  int node0 = b * NPB;
  int nloc = min(NPB, NN - node0);
  const uint2* p = pairs + (size_t)g * CAP2;
  __shared__ int hist[512], pref[512], cur[512], stmp[256];
  for (int i = tid; i < 512; i += 256) hist[i] = 0;
  __syncthreads();
  for (int e = tid; e < count; e += 256)
    atomicAdd(&hist[(int)p[e].y - node0], 1);
  __syncthreads();
  int a0 = hist[2 * tid], a1 = hist[2 * tid + 1];
  int sum = a0 + a1;
  stmp[tid] = sum;
  __syncthreads();
  for (int o = 1; o < 256; o <<= 1) {
    int tv = (tid >= o) ? stmp[tid - o] : 0;
    __syncthreads();
    stmp[tid] += tv;
    __syncthreads();
  }
  int ex = stmp[tid] - sum;
  pref[2 * tid] = ex;       pref[2 * tid + 1] = ex + a0;
  cur[2 * tid] = ex;        cur[2 * tid + 1] = ex + a0;
  __syncthreads();
  for (int i = tid; i < nloc; i += 256)
    rowptr[ch * (NN + 1) + node0 + i] = base + pref[i];
  if (tid == 0 && b == NB2 - 1) rowptr[ch * (NN + 1) + NN] = base + count;
  for (int e = tid; e < count; e += 256) {
    uint2 pr = p[e];
    int pos = atomicAdd(&cur[(int)pr.y - node0], 1);
    col[ch * NE + base + pos] = (int)pr.x;
  }
}

// ---------------- agg (+ fused pool of the PREVIOUS layer's output) ----------------
__global__ __launch_bounds__(256) void agg_pool_kernel(const unsigned short* __restrict__ X,
                                                       const int* __restrict__ rowptr,
                                                       const int* __restrict__ col,
                                                       unsigned short* __restrict__ Y,
                                                       const unsigned short* __restrict__ Xprev,
                                                       const int* __restrict__ gstart,
                                                       float* __restrict__ z, int layerPrev) {
  if (blockIdx.x >= AGGB) {
    // ---- pool role ----
    int pb = blockIdx.x - AGGB;
    int ch = pb >> 6, g = pb & 63;
    int r0 = gstart[ch * (NG + 1) + g], r1 = gstart[ch * (NG + 1) + g + 1];
    int c8 = threadIdx.x & 15, part = threadIdx.x >> 4;
    const uint4* X4 = reinterpret_cast<const uint4*>(Xprev);
    size_t base = (size_t)ch * NN * 16 + c8;
    float acc[8];
#pragma unroll
    for (int q = 0; q < 8; q++) acc[q] = 0.f;
    int r = r0 + part;
    for (; r + 48 < r1; r += 64) {
      uint4 v0 = X4[base + (size_t)r * 16];
      uint4 v1 = X4[base + (size_t)(r + 16) * 16];
      uint4 v2 = X4[base + (size_t)(r + 32) * 16];
      uint4 v3 = X4[base + (size_t)(r + 48) * 16];
      unsigned int w0[4] = {v0.x, v0.y, v0.z, v0.w};
      unsigned int w1[4] = {v1.x, v1.y, v1.z, v1.w};
      unsigned int w2[4] = {v2.x, v2.y, v2.z, v2.w};
      unsigned int w3[4] = {v3.x, v3.y, v3.z, v3.w};
#pragma unroll
      for (int q = 0; q < 4; q++) {
        acc[2 * q]     += bflo(w0[q]) + bflo(w1[q]) + bflo(w2[q]) + bflo(w3[q]);
        acc[2 * q + 1] += bfhi(w0[q]) + bfhi(w1[q]) + bfhi(w2[q]) + bfhi(w3[q]);
      }
    }
    for (; r < r1; r += 16) {
      uint4 v = X4[base + (size_t)r * 16];
      unsigned int w[4] = {v.x, v.y, v.z, v.w};
#pragma unroll
      for (int q = 0; q < 4; q++) {
        acc[2 * q]     += bflo(w[q]);
        acc[2 * q + 1] += bfhi(w[q]);
      }
    }
    __shared__ float zacc[16][128];
#pragma unroll
    for (int q = 0; q < 8; q++) zacc[part][c8 * 8 + q] = acc[q];
    __syncthreads();
    for (int s = 8; s > 0; s >>= 1) {
      if (part < s) {
#pragma unroll
        for (int q = 0; q < 8; q++)
          zacc[part][c8 * 8 + q] += zacc[part + s][c8 * 8 + q];
      }
      __syncthreads();
    }
    if (part == 0) {
#pragma unroll
      for (int q = 0; q < 8; q++) {
        int colw = c8 * 8 + q;
        z[(size_t)g * ZW + ch * DD * NL + layerPrev * DD + colw] = zacc[0][colw];
      }
    }
    return;
  }
  // ---- agg role: XCD-channel-affine, 8-deep pipelined gather ----
  int ch = ((blockIdx.x & 7) >= 4);          // XCDs 0-3 -> ch0, 4-7 -> ch1
  int tile = (blockIdx.x >> 3) * 4 + (blockIdx.x & 3);
  if (tile >= TILES) return;                 // 3 spare blocks per channel
  int nl = tile * 16 + (threadIdx.x >> 4);   // node within channel
  int node = ch * NN + nl;
  int lane = threadIdx.x & 15;
  const int* rp = rowptr + ch * (NN + 1);
  const int* cl = col + ch * NE;
  const uint4* X4 = reinterpret_cast<const uint4*>(X);
  size_t chbase = (size_t)ch * NN * 16;
  float acc[8];
  {
    uint4 sv = X4[(size_t)node * 16 + lane];
    unsigned int w[4] = {sv.x, sv.y, sv.z, sv.w};
#pragma unroll
    for (int q = 0; q < 4; q++) {
      acc[2 * q]     = bflo(w[q]);
      acc[2 * q + 1] = bfhi(w[q]);
    }
  }
  int s = rp[nl], e = rp[nl + 1];
  int j = s;
  for (; j + 8 <= e; j += 8) {
    uint4 v[8];
#pragma unroll
    for (int q = 0; q < 8; q++)
      v[q] = X4[chbase + (size_t)cl[j + q] * 16 + lane];
#pragma unroll
    for (int q = 0; q < 8; q++) {
      unsigned int w[4] = {v[q].x, v[q].y, v[q].z, v[q].w};
#pragma unroll
      for (int u = 0; u < 4; u++) {
        acc[2 * u]     += bflo(w[u]);
        acc[2 * u + 1] += bfhi(w[u]);
      }
    }
  }
  for (; j < e; ++j) {
    uint4 v = X4[chbase + (size_t)cl[j] * 16 + lane];
    unsigned int w[4] = {v.x, v.y, v.z, v.w};
#pragma unroll
    for (int u = 0; u < 4; u++) {
      acc[2 * u]     += bflo(w[u]);
      acc[2 * u + 1] += bfhi(w[u]);
    }
  }
  uint4v o;
  o.x = (unsigned int)f2bf(acc[0]) | ((unsigned int)f2bf(acc[1]) << 16);
  o.y = (unsigned int)f2bf(acc[2]) | ((unsigned int)f2bf(acc[3]) << 16);
  o.z = (unsigned int)f2bf(acc[4]) | ((unsigned int)f2bf(acc[5]) << 16);
  o.w = (unsigned int)f2bf(acc[6]) | ((unsigned int)f2bf(acc[7]) << 16);
  __builtin_nontemporal_store(o, reinterpret_cast<uint4v*>(Y) + (size_t)node * 16 + lane);
}

// ---------------- fused MLP: grid-stride, next-tile prefetch (round-14 form) ----------------
__global__ __launch_bounds__(256) void gemm_fused_kernel(
    const unsigned short* __restrict__ Y, unsigned short* __restrict__ X,
    const unsigned short* __restrict__ WT,
    const float* __restrict__ b1c1, const float* __restrict__ b1c2,
    const float* __restrict__ b2c1, const float* __restrict__ b2c2,
    const float* __restrict__ bng, const float* __restrict__ bnb,
    const float* __restrict__ bnm, const float* __restrict__ bnv, int layer) {
  __shared__ unsigned short hlds[16][136];
  int ch = blockIdx.x >= GB2;
  int lane = threadIdx.x & 63, wv = threadIdx.x >> 6;
  int l15 = lane & 15, lk = lane >> 4;
  int c0 = wv * 32;
  const unsigned short* W1 = WT + (size_t)(ch * 6 + layer) * 16384;
  const unsigned short* W2 = WT + (size_t)(ch * 6 + 3 + layer) * 16384;
  short8 w1f[2][4], w2f[2][4];
#pragma unroll
  for (int ct = 0; ct < 2; ct++)
#pragma unroll
    for (int kk = 0; kk < 4; kk++) {
      size_t boff = (size_t)(c0 + ct * 16 + l15) * 128 + kk * 32 + lk * 8;
      w1f[ct][kk] = *reinterpret_cast<const short8*>(W1 + boff);
      w2f[ct][kk] = *reinterpret_cast<const short8*>(W2 + boff);
    }
  const float* b1 = (ch ? b1c2 : b1c1) + layer * DD;
  const float* b2 = (ch ? b2c2 : b2c1) + layer * DD;
  float sc1[2], sh1[2], sh2[2];
#pragma unroll
  for (int ct = 0; ct < 2; ct++) {
    int colg = c0 + ct * 16 + l15;
    if (!ch) {
      float s = bng[layer * DD + colg] * rsqrtf(bnv[layer * DD + colg] + 1e-5f);
      sc1[ct] = s;
      sh1[ct] = (b1[colg] - bnm[layer * DD + colg]) * s + bnb[layer * DD + colg];
    } else {
      sc1[ct] = 1.f;
      sh1[ct] = b1[colg];
    }
    sh2[ct] = b2[colg];
  }
  int t0 = ch ? blockIdx.x - GB2 : blockIdx.x;
  short8 a0, a1, a2, a3;
  {
    size_t r0g = (size_t)ch * NN + t0 * 16;
    const unsigned short* yp = Y + (r0g + l15) * 128 + lk * 8;
    a0 = *reinterpret_cast<const short8*>(yp);
    a1 = *reinterpret_cast<const short8*>(yp + 32);
    a2 = *reinterpret_cast<const short8*>(yp + 64);
    a3 = *reinterpret_cast<const short8*>(yp + 96);
  }
  for (int t = t0; t < TILES; t += GB2) {
    int r0l = t * 16;
    size_t r0g = (size_t)ch * NN + r0l;
    short8 n0, n1, n2, n3;
    int tn = t + GB2;
    if (tn < TILES) {
      const unsigned short* yp = Y + ((size_t)ch * NN + tn * 16 + l15) * 128 + lk * 8;
      n0 = *reinterpret_cast<const short8*>(yp);
      n1 = *reinterpret_cast<const short8*>(yp + 32);
      n2 = *reinterpret_cast<const short8*>(yp + 64);
      n3 = *reinterpret_cast<const short8*>(yp + 96);
    }
#pragma unroll
    for (int ct = 0; ct < 2; ct++) {
      f32x4 acc = {0.f, 0.f, 0.f, 0.f};
      acc = __builtin_amdgcn_mfma_f32_16x16x32_bf16(a0, w1f[ct][0], acc, 0, 0, 0);
      acc = __builtin_amdgcn_mfma_f32_16x16x32_bf16(a1, w1f[ct][1], acc, 0, 0, 0);
      acc = __builtin_amdgcn_mfma_f32_16x16x32_bf16(a2, w1f[ct][2], acc, 0, 0, 0);
      acc = __builtin_amdgcn_mfma_f32_16x16x32_bf16(a3, w1f[ct][3], acc, 0, 0, 0);
      int colg = c0 + ct * 16 + l15;
#pragma unroll
      for (int r = 0; r < 4; r++) {
        float tv = fmaxf(acc[r] * sc1[ct] + sh1[ct], 0.f);
        hlds[lk * 4 + r][colg] = f2bf(tv);
      }
    }
    __syncthreads();
    short8 h0 = *reinterpret_cast<const short8*>(&hlds[l15][lk * 8]);
    short8 h1 = *reinterpret_cast<const short8*>(&hlds[l15][32 + lk * 8]);
    short8 h2 = *reinterpret_cast<const short8*>(&hlds[l15][64 + lk * 8]);
    short8 h3 = *reinterpret_cast<const short8*>(&hlds[l15][96 + lk * 8]);
#pragma unroll
    for (int ct = 0; ct < 2; ct++) {
      f32x4 acc = {0.f, 0.f, 0.f, 0.f};
      acc = __builtin_amdgcn_mfma_f32_16x16x32_bf16(h0, w2f[ct][0], acc, 0, 0, 0);
      acc = __builtin_amdgcn_mfma_f32_16x16x32_bf16(h1, w2f[ct][1], acc, 0, 0, 0);
      acc = __builtin_amdgcn_mfma_f32_16x16x32_bf16(h2, w2f[ct][2], acc, 0, 0, 0);
      acc = __builtin_amdgcn_mfma_f32_16x16x32_bf16(h3, w2f[ct][3], acc, 0, 0, 0);
      int colg = c0 + ct * 16 + l15;
#pragma unroll
      for (int r = 0; r < 4; r++) {
        float tv = acc[r] + sh2[ct];
        if (!ch) tv = fmaxf(tv, 0.f);
        else     tv = tv > 0.f ? tv : 0.01f * tv;
        X[(r0g + lk * 4 + r) * 128 + colg] = f2bf(tv);
      }
    }
    __syncthreads();
    a0 = n0; a1 = n1; a2 = n2; a3 = n3;
  }
}

// ---------------- standalone pool (last layer) ----------------
__global__ __launch_bounds__(256) void pool_kernel(const unsigned short* __restrict__ X,
                                                   const int* __restrict__ gstart,
                                                   float* __restrict__ z, int layer) {
  int ch = blockIdx.x >> 6, g = blockIdx.x & 63;
  int r0 = gstart[ch * (NG + 1) + g], r1 = gstart[ch * (NG + 1) + g + 1];
  int c8 = threadIdx.x & 15, part = threadIdx.x >> 4;
  const uint4* X4 = reinterpret_cast<const uint4*>(X);
  size_t base = (size_t)ch * NN * 16 + c8;
  float acc[8];
#pragma unroll
  for (int q = 0; q < 8; q++) acc[q] = 0.f;
  int r = r0 + part;
  for (; r + 48 < r1; r += 64) {
    uint4 v0 = X4[base + (size_t)r * 16];
    uint4 v1 = X4[base + (size_t)(r + 16) * 16];
    uint4 v2 = X4[base + (size_t)(r + 32) * 16];
    uint4 v3 = X4[base + (size_t)(r + 48) * 16];
    unsigned int w0[4] = {v0.x, v0.y, v0.z, v0.w};
    unsigned int w1[4] = {v1.x, v1.y, v1.z, v1.w};
    unsigned int w2[4] = {v2.x, v2.y, v2.z, v2.w};
    unsigned int w3[4] = {v3.x, v3.y, v3.z, v3.w};
#pragma unroll
    for (int q = 0; q < 4; q++) {
      acc[2 * q]     += bflo(w0[q]) + bflo(w1[q]) + bflo(w2[q]) + bflo(w3[q]);
      acc[2 * q + 1] += bfhi(w0[q]) + bfhi(w1[q]) + bfhi(w2[q]) + bfhi(w3[q]);
    }
  }
  for (; r < r1; r += 16) {
    uint4 v = X4[base + (size_t)r * 16];
    unsigned int w[4] = {v.x, v.y, v.z, v.w};
#pragma unroll
    for (int q = 0; q < 4; q++) {
      acc[2 * q]     += bflo(w[q]);
      acc[2 * q + 1] += bfhi(w[q]);
    }
  }
  __shared__ float zacc[16][128];
#pragma unroll
  for (int q = 0; q < 8; q++) zacc[part][c8 * 8 + q] = acc[q];
  __syncthreads();
  for (int s = 8; s > 0; s >>= 1) {
    if (part < s) {
#pragma unroll
      for (int q = 0; q < 8; q++)
        zacc[part][c8 * 8 + q] += zacc[part + s][c8 * 8 + q];
    }
    __syncthreads();
  }
  if (part == 0) {
#pragma unroll
    for (int q = 0; q < 8; q++) {
      int colw = c8 * 8 + q;
      z[(size_t)g * ZW + ch * DD * NL + layer * DD + colw] = zacc[0][colw];
    }
  }
}

// ---------------- head ----------------
__global__ __launch_bounds__(128) void head_kernel(const float* __restrict__ z,
                                                   const float* __restrict__ Wf1,
                                                   const float* __restrict__ bf1,
                                                   const float* __restrict__ Wf2,
                                                   const float* __restrict__ bf2,
                                                   float* __restrict__ out) {
  int g = blockIdx.x, t = threadIdx.x;
  const float* zr = z + (size_t)g * ZW;
  float acc = bf1[t];
  for (int j = 0; j < ZW; ++j) acc += zr[j] * Wf1[(size_t)j * DD + t];
  float h = fmaxf(acc, 0.f);
  __shared__ float red[128];
  red[t] = h * Wf2[t];
  __syncthreads();
  for (int s = 64; s > 0; s >>= 1) {
    if (t < s) red[t] += red[t + s];
    __syncthreads();
  }
  if (t == 0) out[g] = red[0] + bf2[0];
}

extern "C" void kernel_launch(void* const* d_in, const int* in_sizes, int n_in,
                              void* d_out, int out_size, void* d_ws, size_t ws_size,
                              hipStream_t stream) {
  const float* x1   = (const float*)d_in[0];
  const float* x2   = (const float*)d_in[1];
  const float* W1c1 = (const float*)d_in[2];
  const float* b1c1 = (const float*)d_in[3];
  const float* bng  = (const float*)d_in[4];
  const float* bnb  = (const float*)d_in[5];
  const float* bnm  = (const float*)d_in[6];
  const float* bnv  = (const float*)d_in[7];
  const float* W2c1 = (const float*)d_in[8];
  const float* b2c1 = (const float*)d_in[9];
  const float* W1c2 = (const float*)d_in[10];
  const float* b1c2 = (const float*)d_in[11];
  const float* W2c2 = (const float*)d_in[12];
  const float* b2c2 = (const float*)d_in[13];
  const float* Wf1  = (const float*)d_in[14];
  const float* bf1  = (const float*)d_in[15];
  const float* Wf2  = (const float*)d_in[16];
  const float* bf2  = (const float*)d_in[17];
  const int* edge1  = (const int*)d_in[18];
  const int* edge2  = (const int*)d_in[19];
  const int* batch1 = (const int*)d_in[20];
  const int* batch2 = (const int*)d_in[21];
  (void)ws_size; (void)n_in; (void)in_sizes; (void)out_size;

  char* ws = (char*)d_ws;
  const size_t NB16 = (size_t)TOTN * DD * 2;  // 25.6 MB node buffer
  unsigned short* bufA = (unsigned short*)(ws);
  unsigned short* bufB = (unsigned short*)(ws + NB16);
  unsigned short* bufY = (unsigned short*)(ws + 2 * NB16);
  size_t off = 3 * NB16;
  unsigned short* WT = (unsigned short*)(ws + off); off += (size_t)12 * 16384 * 2;
  uint2* pairs = (uint2*)(ws + off); off += (size_t)2 * NB2 * CAP2 * 8;
  int* col     = (int*)(ws + off); off += (size_t)2 * NE * 4;
  int* rowptr  = (int*)(ws + off); off += (((size_t)2 * (NN + 1) * 4) + 255) & ~(size_t)255;
  int* bcur    = (int*)(ws + off); off += 256 * 4;
  int* gstart  = (int*)(ws + off); off += 256 * 4;
  float* z     = (float*)(ws + off); off += (size_t)NG * ZW * 4;

  (void)hipMemsetAsync(bcur, 0, 256 * 4, stream);
  prep_kernel<<<CVTX + 192 + 2 * P1B, 256, 0, stream>>>(
      x1, x2, bufA, W1c1, W2c1, W1c2, W2c2, WT, edge1, edge2, bcur, pairs);
  csr_build_kernel<<<257, 256, 0, stream>>>(pairs, bcur, rowptr, col, batch1, batch2, gstart);

  unsigned short* cin = bufA;
  unsigned short* cout = bufB;
  for (int i = 0; i < NL; ++i) {
    int grid = (i == 0) ? AGGB : AGGB + 2 * NG;  // layers 1,2 carry prev layer's pool
    agg_pool_kernel<<<grid, 256, 0, stream>>>(cin, rowptr, col, bufY,
                                              cin, gstart, z, i - 1);
    gemm_fused_kernel<<<2 * GB2, 256, 0, stream>>>(bufY, cout, WT,
                                                   b1c1, b1c2, b2c1, b2c2,
                                                   bng, bnb, bnm, bnv, i);
    unsigned short* tmp = cin; cin = cout; cout = tmp;
  }
  pool_kernel<<<2 * NG, 256, 0, stream>>>(cin, gstart, z, NL - 1);
  head_kernel<<<NG, 128, 0, stream>>>(z, Wf1, bf1, Wf2, bf2, (float*)d_out);
}